// Round 5
// baseline (126.121 us; speedup 1.0000x reference)
//
#include <hip/hip_runtime.h>
#include <math.h>

#define T_TOK 8192
#define HID   2880
#define NE    128
#define TOPK  4
#define NKS   (HID / 32)     // 90 K-steps of 32
#define LROW  40             // LDS row stride in halves (80 B): b128 frag reads = 8 words/bank (optimal)
#define LPLANE (128 * LROW)  // one h- or l-plane of the x tile, in halves

typedef _Float16 f16x8 __attribute__((ext_vector_type(8)));
typedef float    f32x4 __attribute__((ext_vector_type(4)));

// ---------------------------------------------------------------------------
// Kernel 0: W (fp32) -> fragment-linear fp16 hi/lo planes, scaled x32 (keeps
// lo out of denormals; 2^-5 folded into GEMM epilogue). Fragment (k-step gs,
// expert-group j, plane p) at ((gs*8+j)*2+p)*512 halves; lane l=(oct<<4)|(n&15)
// holds 8 k-consecutive halves = the mfma_16x16x32 B-operand chunk.
// Also zeroes the counts region (block 0) so topk can atomicAdd into it.
// ---------------------------------------------------------------------------
__global__ __launch_bounds__(256) void convert_w(const float* __restrict__ w,
                                                 _Float16* __restrict__ wc,
                                                 float* __restrict__ counts) {
  if (blockIdx.x == 0 && threadIdx.x < NE) counts[threadIdx.x] = 0.0f;
  const int c = blockIdx.x * 256 + threadIdx.x;   // one 8-k chunk of one expert
  if (c >= NE * (HID / 8)) return;
  const int n  = c / (HID / 8);
  const int k8 = c % (HID / 8);
  const float4 v0 = *(const float4*)(w + (size_t)n * HID + k8 * 8);
  const float4 v1 = *(const float4*)(w + (size_t)n * HID + k8 * 8 + 4);
  const float f[8] = {v0.x, v0.y, v0.z, v0.w, v1.x, v1.y, v1.z, v1.w};
  f16x8 h, l;
#pragma unroll
  for (int i = 0; i < 8; ++i) {
    const float s = f[i] * 32.0f;
    const _Float16 hi = (_Float16)s;
    h[i] = hi;
    l[i] = (_Float16)(s - (float)hi);
  }
  const int gs   = k8 >> 2;
  const int oct  = k8 & 3;
  const int j    = n >> 4;
  const int lane = (oct << 4) | (n & 15);
  _Float16* base = wc + ((size_t)(gs * 8 + j) * 2) * 512 + lane * 8;
  *(f16x8*)(base)       = h;
  *(f16x8*)(base + 512) = l;
}

// ---------------------------------------------------------------------------
// Kernel 1: partial logits via fp16x2 MFMA emulation of fp32:
// acc += xh*wh + xl*wh + xh*wl, result * 2^-5. Tile 128x128, 4 waves (2x2),
// 4x4 frags/wave. Double-buffered LDS (one barrier/step); x prefetched ~2
// steps ahead (HBM), B fragments 1 step ahead (L2-hot). Split-K planes.
// ---------------------------------------------------------------------------
__device__ __forceinline__ void load_x(const float* __restrict__ x, int m0,
                                       int srow, int skh, int gs, float4 (&xr)[4]) {
  const float* xp = x + (size_t)(m0 + srow) * HID + gs * 32 + skh * 16;
#pragma unroll
  for (int q = 0; q < 4; ++q) xr[q] = *(const float4*)(xp + q * 4);
}

__device__ __forceinline__ void load_b(const _Float16* __restrict__ wc, int wn,
                                       int lane, int gs, f16x8 (&bh)[4], f16x8 (&bl)[4]) {
  const _Float16* bp = wc + ((size_t)gs * 8 + wn * 4) * 2 * 512 + lane * 8;
#pragma unroll
  for (int nj = 0; nj < 4; ++nj) {
    bh[nj] = *(const f16x8*)(bp + (size_t)nj * 1024);
    bl[nj] = *(const f16x8*)(bp + (size_t)nj * 1024 + 512);
  }
}

__device__ __forceinline__ void stage_x(const float4 (&xr)[4], _Float16* __restrict__ buf,
                                        int srow, int skh) {
  union { float4 v[4]; float f[16]; } u;
  u.v[0] = xr[0]; u.v[1] = xr[1]; u.v[2] = xr[2]; u.v[3] = xr[3];
  f16x8 h0, h1, l0, l1;
#pragma unroll
  for (int i = 0; i < 8; ++i) {
    const float a = u.f[i];
    const _Float16 ha = (_Float16)a;
    h0[i] = ha; l0[i] = (_Float16)(a - (float)ha);
    const float b = u.f[i + 8];
    const _Float16 hb = (_Float16)b;
    h1[i] = hb; l1[i] = (_Float16)(b - (float)hb);
  }
  const int off = srow * LROW + skh * 16;
  *(f16x8*)&buf[off]              = h0;
  *(f16x8*)&buf[off + 8]          = h1;
  *(f16x8*)&buf[LPLANE + off]     = l0;
  *(f16x8*)&buf[LPLANE + off + 8] = l1;
}

__device__ __forceinline__ void mfma_step(const _Float16* __restrict__ buf,
                                          const f16x8 (&bh)[4], const f16x8 (&bl)[4],
                                          int wm, int lane, f32x4 (&acc)[4][4]) {
#pragma unroll
  for (int mi = 0; mi < 4; ++mi) {
    const int off = (wm * 64 + mi * 16 + (lane & 15)) * LROW + (lane >> 4) * 8;
    const f16x8 ah = *(const f16x8*)&buf[off];
    const f16x8 al = *(const f16x8*)&buf[LPLANE + off];
#pragma unroll
    for (int nj = 0; nj < 4; ++nj) {
      acc[mi][nj] = __builtin_amdgcn_mfma_f32_16x16x32_f16(ah, bh[nj], acc[mi][nj], 0, 0, 0);
      acc[mi][nj] = __builtin_amdgcn_mfma_f32_16x16x32_f16(al, bh[nj], acc[mi][nj], 0, 0, 0);
      acc[mi][nj] = __builtin_amdgcn_mfma_f32_16x16x32_f16(ah, bl[nj], acc[mi][nj], 0, 0, 0);
    }
  }
}

__global__ __launch_bounds__(256, 2) void logits_mfma(const float* __restrict__ x,
                                                      const _Float16* __restrict__ wc,
                                                      float* __restrict__ part,
                                                      int split) {
  __shared__ _Float16 xsh[2 * 2 * LPLANE];   // [buf][plane][row][LROW] = 40 KB

  const int t    = threadIdx.x;
  const int s    = blockIdx.x % split;
  const int tile = blockIdx.x / split;
  const int m0   = tile * 128;

  const int lane = t & 63;
  const int wv   = t >> 6;
  const int wm   = wv >> 1;
  const int wn   = wv & 1;

  const int kbase = NKS / split, krem = NKS % split;
  const int cnt   = kbase + (s < krem ? 1 : 0);
  const int st0   = s * kbase + (s < krem ? s : krem);

  const int srow = t >> 1;
  const int skh  = t & 1;

  _Float16* buf0 = xsh;
  _Float16* buf1 = xsh + 2 * LPLANE;

  f32x4 acc[4][4] = {};
  float4 xrA[4], xrB[4];
  f16x8 bAh[4], bAl[4], bBh[4], bBl[4];

  // prologue: step 0 staged into buf0; x for step 1 in flight; B(0) in regs
  load_x(x, m0, srow, skh, st0, xrA);
  load_b(wc, wn, lane, st0, bAh, bAl);
  stage_x(xrA, buf0, srow, skh);
  if (cnt > 1) load_x(x, m0, srow, skh, st0 + 1, xrB);
  __syncthreads();

  int st = 0;
  for (;;) {
    // ---- even-slot step st: compute buf0/bA; stage st+1 into buf1 ----
    if (st + 1 < cnt) load_b(wc, wn, lane, st0 + st + 1, bBh, bBl);
    if (st + 2 < cnt) load_x(x, m0, srow, skh, st0 + st + 2, xrA);
    mfma_step(buf0, bAh, bAl, wm, lane, acc);
    if (st + 1 < cnt) stage_x(xrB, buf1, srow, skh);
    __syncthreads();
    if (st + 1 >= cnt) break;

    // ---- odd-slot step st+1: compute buf1/bB; stage st+2 into buf0 ----
    if (st + 2 < cnt) load_b(wc, wn, lane, st0 + st + 2, bAh, bAl);
    if (st + 3 < cnt) load_x(x, m0, srow, skh, st0 + st + 3, xrB);
    mfma_step(buf1, bBh, bBl, wm, lane, acc);
    if (st + 2 < cnt) stage_x(xrA, buf0, srow, skh);
    __syncthreads();
    st += 2;
    if (st >= cnt) break;
  }

  // epilogue: C/D layout col=lane&15 (expert), row=(lane>>4)*4+reg (token)
  float* pl = part + (size_t)s * T_TOK * NE;
  const int r0 = m0 + wm * 64 + (lane >> 4) * 4;
  const int e0 = wn * 64 + (lane & 15);
#pragma unroll
  for (int mi = 0; mi < 4; ++mi)
#pragma unroll
    for (int nj = 0; nj < 4; ++nj) {
      float* pp = pl + (size_t)(r0 + mi * 16) * NE + e0 + nj * 16;
#pragma unroll
      for (int r = 0; r < 4; ++r) pp[(size_t)r * NE] = acc[mi][nj][r] * 0.03125f;
    }
}

// ---------------------------------------------------------------------------
// Kernel 2: reduce split-K partials in fixed order + bias, per-token top-4
// (desc, lower-index tie-break = jax.lax.top_k), softmax over the 4, and
// histogram via fp32 atomicAdd of 1.0 (exact integers, order-independent).
// One wave per token.
// Out: [0,T*4) scores | [T*4,2*T*4) indices-as-float | [2*T*4,+128) counts
// ---------------------------------------------------------------------------
__global__ __launch_bounds__(256) void topk_kernel(const float* __restrict__ part,
                                                   const float* __restrict__ bias,
                                                   float* __restrict__ out,
                                                   int split) {
  const int lane = threadIdx.x & 63;
  const int wave = threadIdx.x >> 6;
  const int tok  = blockIdx.x * 4 + wave;

  float v0 = 0.f, v1 = 0.f;
  for (int s = 0; s < split; ++s) {   // fixed order -> deterministic
    const float* prow = part + (size_t)s * T_TOK * NE + (size_t)tok * NE;
    v0 += prow[lane];
    v1 += prow[lane + 64];
  }
  v0 += bias[lane];
  v1 += bias[lane + 64];
  const int i0 = lane, i1 = lane + 64;

  float topv[TOPK];
  int   topi[TOPK];

#pragma unroll
  for (int r = 0; r < TOPK; ++r) {
    float bv; int bi;
    if (v0 >= v1) { bv = v0; bi = i0; }   // i0 < i1 implements lower-index tie-break
    else          { bv = v1; bi = i1; }
#pragma unroll
    for (int off = 32; off > 0; off >>= 1) {
      const float ov = __shfl_xor(bv, off);
      const int   oi = __shfl_xor(bi, off);
      if (ov > bv || (ov == bv && oi < bi)) { bv = ov; bi = oi; }
    }
    topv[r] = bv; topi[r] = bi;
    if (bi == i0) v0 = -INFINITY;
    if (bi == i1) v1 = -INFINITY;
  }

  const float m = topv[0];
  float sum = 0.f;
#pragma unroll
  for (int r = 0; r < TOPK; ++r) sum += expf(topv[r] - m);

  if (lane < TOPK) {
    out[(size_t)tok * TOPK + lane] = expf(topv[lane] - m) / sum;
    out[(size_t)T_TOK * TOPK + (size_t)tok * TOPK + lane] = (float)topi[lane];
    atomicAdd(out + 2 * (size_t)T_TOK * TOPK + topi[lane], 1.0f);
  }
}

extern "C" void kernel_launch(void* const* d_in, const int* in_sizes, int n_in,
                              void* d_out, int out_size, void* d_ws, size_t ws_size,
                              hipStream_t stream) {
  const float* x    = (const float*)d_in[0];
  const float* w    = (const float*)d_in[1];
  const float* bias = (const float*)d_in[2];
  float* out  = (float*)d_out;
  float* part = (float*)d_ws;

  const size_t plane  = (size_t)T_TOK * NE * sizeof(float);        // 4 MB
  const size_t wbytes = (size_t)NE * HID * 2 * sizeof(_Float16);   // 1.44 MB

  int split = (int)((ws_size - wbytes) / plane);
  if (split > 8) split = 8;
  if (split < 1) split = 1;

  _Float16* wc    = (_Float16*)((char*)d_ws + (size_t)split * plane);
  float*    cnts  = out + 2 * (size_t)T_TOK * TOPK;

  convert_w<<<(NE * (HID / 8) + 255) / 256, 256, 0, stream>>>(w, wc, cnts);
  logits_mfma<<<(T_TOK / 128) * split, 256, 0, stream>>>(x, wc, part, split);
  topk_kernel<<<T_TOK / 4, 256, 0, stream>>>(part, bias, out, split);
}

// Round 6
// 65.842 us; speedup vs baseline: 1.9155x; 1.9155x over previous
//
#include <hip/hip_runtime.h>
#include <math.h>

#define T_TOK 8192
#define HID   2880
#define NE    128
#define TOPK  4
#define NKS   (HID / 32)     // 90 K-steps of 32
#define LROW  40             // LDS row stride in halves (80 B): b128 frag reads = 8 words/bank (optimal)
#define LPLANE (128 * LROW)  // one h- or l-plane of the x tile, in halves

typedef _Float16 f16x8 __attribute__((ext_vector_type(8)));
typedef float    f32x4 __attribute__((ext_vector_type(4)));

// ---------------------------------------------------------------------------
// Kernel 0: W (fp32) -> fragment-linear fp16 hi/lo planes, scaled x32 (keeps
// lo out of denormals; 2^-5 folded into GEMM epilogue). Fragment (k-step gs,
// expert-group j, plane p) at ((gs*8+j)*2+p)*512 halves; lane l=(oct<<4)|(n&15)
// holds 8 k-consecutive halves = the mfma_16x16x32 B-operand chunk.
// ---------------------------------------------------------------------------
__global__ __launch_bounds__(256) void convert_w(const float* __restrict__ w,
                                                 _Float16* __restrict__ wc) {
  const int c = blockIdx.x * 256 + threadIdx.x;   // one 8-k chunk of one expert
  if (c >= NE * (HID / 8)) return;
  const int n  = c / (HID / 8);
  const int k8 = c % (HID / 8);
  const float4 v0 = *(const float4*)(w + (size_t)n * HID + k8 * 8);
  const float4 v1 = *(const float4*)(w + (size_t)n * HID + k8 * 8 + 4);
  const float f[8] = {v0.x, v0.y, v0.z, v0.w, v1.x, v1.y, v1.z, v1.w};
  f16x8 h, l;
#pragma unroll
  for (int i = 0; i < 8; ++i) {
    const float s = f[i] * 32.0f;
    const _Float16 hi = (_Float16)s;
    h[i] = hi;
    l[i] = (_Float16)(s - (float)hi);
  }
  const int gs   = k8 >> 2;
  const int oct  = k8 & 3;
  const int j    = n >> 4;
  const int lane = (oct << 4) | (n & 15);
  _Float16* base = wc + ((size_t)(gs * 8 + j) * 2) * 512 + lane * 8;
  *(f16x8*)(base)       = h;
  *(f16x8*)(base + 512) = l;
}

// ---------------------------------------------------------------------------
// Kernel 1: partial logits via fp16x2 MFMA emulation of fp32:
// acc += xh*wh + xl*wh + xh*wl, result * 2^-5. Tile 128x128, 4 waves (2x2),
// 4x4 frags/wave. Double-buffered LDS (one barrier/step); x prefetched ~2
// steps ahead (HBM), B fragments 1 step ahead (L2-hot). Split-K planes.
// ---------------------------------------------------------------------------
__device__ __forceinline__ void load_x(const float* __restrict__ x, int m0,
                                       int srow, int skh, int gs, float4 (&xr)[4]) {
  const float* xp = x + (size_t)(m0 + srow) * HID + gs * 32 + skh * 16;
#pragma unroll
  for (int q = 0; q < 4; ++q) xr[q] = *(const float4*)(xp + q * 4);
}

__device__ __forceinline__ void load_b(const _Float16* __restrict__ wc, int wn,
                                       int lane, int gs, f16x8 (&bh)[4], f16x8 (&bl)[4]) {
  const _Float16* bp = wc + ((size_t)gs * 8 + wn * 4) * 2 * 512 + lane * 8;
#pragma unroll
  for (int nj = 0; nj < 4; ++nj) {
    bh[nj] = *(const f16x8*)(bp + (size_t)nj * 1024);
    bl[nj] = *(const f16x8*)(bp + (size_t)nj * 1024 + 512);
  }
}

__device__ __forceinline__ void stage_x(const float4 (&xr)[4], _Float16* __restrict__ buf,
                                        int srow, int skh) {
  union { float4 v[4]; float f[16]; } u;
  u.v[0] = xr[0]; u.v[1] = xr[1]; u.v[2] = xr[2]; u.v[3] = xr[3];
  f16x8 h0, h1, l0, l1;
#pragma unroll
  for (int i = 0; i < 8; ++i) {
    const float a = u.f[i];
    const _Float16 ha = (_Float16)a;
    h0[i] = ha; l0[i] = (_Float16)(a - (float)ha);
    const float b = u.f[i + 8];
    const _Float16 hb = (_Float16)b;
    h1[i] = hb; l1[i] = (_Float16)(b - (float)hb);
  }
  const int off = srow * LROW + skh * 16;
  *(f16x8*)&buf[off]              = h0;
  *(f16x8*)&buf[off + 8]          = h1;
  *(f16x8*)&buf[LPLANE + off]     = l0;
  *(f16x8*)&buf[LPLANE + off + 8] = l1;
}

__device__ __forceinline__ void mfma_step(const _Float16* __restrict__ buf,
                                          const f16x8 (&bh)[4], const f16x8 (&bl)[4],
                                          int wm, int lane, f32x4 (&acc)[4][4]) {
#pragma unroll
  for (int mi = 0; mi < 4; ++mi) {
    const int off = (wm * 64 + mi * 16 + (lane & 15)) * LROW + (lane >> 4) * 8;
    const f16x8 ah = *(const f16x8*)&buf[off];
    const f16x8 al = *(const f16x8*)&buf[LPLANE + off];
#pragma unroll
    for (int nj = 0; nj < 4; ++nj) {
      acc[mi][nj] = __builtin_amdgcn_mfma_f32_16x16x32_f16(ah, bh[nj], acc[mi][nj], 0, 0, 0);
      acc[mi][nj] = __builtin_amdgcn_mfma_f32_16x16x32_f16(al, bh[nj], acc[mi][nj], 0, 0, 0);
      acc[mi][nj] = __builtin_amdgcn_mfma_f32_16x16x32_f16(ah, bl[nj], acc[mi][nj], 0, 0, 0);
    }
  }
}

__global__ __launch_bounds__(256, 2) void logits_mfma(const float* __restrict__ x,
                                                      const _Float16* __restrict__ wc,
                                                      float* __restrict__ part,
                                                      int split) {
  __shared__ _Float16 xsh[2 * 2 * LPLANE];   // [buf][plane][row][LROW] = 40 KB

  const int t    = threadIdx.x;
  const int s    = blockIdx.x % split;
  const int tile = blockIdx.x / split;
  const int m0   = tile * 128;

  const int lane = t & 63;
  const int wv   = t >> 6;
  const int wm   = wv >> 1;
  const int wn   = wv & 1;

  const int kbase = NKS / split, krem = NKS % split;
  const int cnt   = kbase + (s < krem ? 1 : 0);
  const int st0   = s * kbase + (s < krem ? s : krem);

  const int srow = t >> 1;
  const int skh  = t & 1;

  _Float16* buf0 = xsh;
  _Float16* buf1 = xsh + 2 * LPLANE;

  f32x4 acc[4][4] = {};
  float4 xrA[4], xrB[4];
  f16x8 bAh[4], bAl[4], bBh[4], bBl[4];

  // prologue: step 0 staged into buf0; x for step 1 in flight; B(0) in regs
  load_x(x, m0, srow, skh, st0, xrA);
  load_b(wc, wn, lane, st0, bAh, bAl);
  stage_x(xrA, buf0, srow, skh);
  if (cnt > 1) load_x(x, m0, srow, skh, st0 + 1, xrB);
  __syncthreads();

  int st = 0;
  for (;;) {
    // ---- even-slot step st: compute buf0/bA; stage st+1 into buf1 ----
    if (st + 1 < cnt) load_b(wc, wn, lane, st0 + st + 1, bBh, bBl);
    if (st + 2 < cnt) load_x(x, m0, srow, skh, st0 + st + 2, xrA);
    mfma_step(buf0, bAh, bAl, wm, lane, acc);
    if (st + 1 < cnt) stage_x(xrB, buf1, srow, skh);
    __syncthreads();
    if (st + 1 >= cnt) break;

    // ---- odd-slot step st+1: compute buf1/bB; stage st+2 into buf0 ----
    if (st + 2 < cnt) load_b(wc, wn, lane, st0 + st + 2, bAh, bAl);
    if (st + 3 < cnt) load_x(x, m0, srow, skh, st0 + st + 3, xrB);
    mfma_step(buf1, bBh, bBl, wm, lane, acc);
    if (st + 2 < cnt) stage_x(xrA, buf0, srow, skh);
    __syncthreads();
    st += 2;
    if (st >= cnt) break;
  }

  // epilogue: C/D layout col=lane&15 (expert), row=(lane>>4)*4+reg (token)
  float* pl = part + (size_t)s * T_TOK * NE;
  const int r0 = m0 + wm * 64 + (lane >> 4) * 4;
  const int e0 = wn * 64 + (lane & 15);
#pragma unroll
  for (int mi = 0; mi < 4; ++mi)
#pragma unroll
    for (int nj = 0; nj < 4; ++nj) {
      float* pp = pl + (size_t)(r0 + mi * 16) * NE + e0 + nj * 16;
#pragma unroll
      for (int r = 0; r < 4; ++r) pp[(size_t)r * NE] = acc[mi][nj][r] * 0.03125f;
    }
}

// ---------------------------------------------------------------------------
// Kernel 2: reduce split-K partials in fixed order + bias, per-token top-4
// (desc, lower-index tie-break = jax.lax.top_k), softmax over the 4.
// NO atomics — 32768 contended cross-XCD atomicAdds cost ~80 us (R5 lesson);
// the histogram is a separate L2-resident scan (kernel 3).
// Out: [0,T*4) scores | [T*4,2*T*4) indices-as-float | [2*T*4,+128) counts
// ---------------------------------------------------------------------------
__global__ __launch_bounds__(256) void topk_kernel(const float* __restrict__ part,
                                                   const float* __restrict__ bias,
                                                   float* __restrict__ out,
                                                   int split) {
  const int lane = threadIdx.x & 63;
  const int wave = threadIdx.x >> 6;
  const int tok  = blockIdx.x * 4 + wave;

  float v0 = 0.f, v1 = 0.f;
  for (int s = 0; s < split; ++s) {   // fixed order -> deterministic
    const float* prow = part + (size_t)s * T_TOK * NE + (size_t)tok * NE;
    v0 += prow[lane];
    v1 += prow[lane + 64];
  }
  v0 += bias[lane];
  v1 += bias[lane + 64];
  const int i0 = lane, i1 = lane + 64;

  float topv[TOPK];
  int   topi[TOPK];

#pragma unroll
  for (int r = 0; r < TOPK; ++r) {
    float bv; int bi;
    if (v0 >= v1) { bv = v0; bi = i0; }   // i0 < i1 implements lower-index tie-break
    else          { bv = v1; bi = i1; }
#pragma unroll
    for (int off = 32; off > 0; off >>= 1) {
      const float ov = __shfl_xor(bv, off);
      const int   oi = __shfl_xor(bi, off);
      if (ov > bv || (ov == bv && oi < bi)) { bv = ov; bi = oi; }
    }
    topv[r] = bv; topi[r] = bi;
    if (bi == i0) v0 = -INFINITY;
    if (bi == i1) v1 = -INFINITY;
  }

  const float m = topv[0];
  float sum = 0.f;
#pragma unroll
  for (int r = 0; r < TOPK; ++r) sum += expf(topv[r] - m);

  if (lane < TOPK) {
    out[(size_t)tok * TOPK + lane] = expf(topv[lane] - m) / sum;
    out[(size_t)T_TOK * TOPK + (size_t)tok * TOPK + lane] = (float)topi[lane];
  }
}

// ---------------------------------------------------------------------------
// Kernel 3: expert histogram, atomic-free & deterministic. One block per
// expert scans the 32768 index floats (128 KB, L2-resident after topk).
// Writes counts[e] directly -> no zero-init needed anywhere.
// ---------------------------------------------------------------------------
__global__ __launch_bounds__(256) void count_kernel(const float* __restrict__ idxf,
                                                    float* __restrict__ counts) {
  const int e = blockIdx.x;
  const int t = threadIdx.x;
  const float ef = (float)e;
  int c = 0;
  for (int i = t; i < T_TOK * TOPK; i += 256)
    c += (idxf[i] == ef) ? 1 : 0;
#pragma unroll
  for (int off = 32; off > 0; off >>= 1) c += __shfl_xor(c, off);
  __shared__ int sh[4];
  if ((t & 63) == 0) sh[t >> 6] = c;
  __syncthreads();
  if (t == 0) counts[e] = (float)(sh[0] + sh[1] + sh[2] + sh[3]);
}

extern "C" void kernel_launch(void* const* d_in, const int* in_sizes, int n_in,
                              void* d_out, int out_size, void* d_ws, size_t ws_size,
                              hipStream_t stream) {
  const float* x    = (const float*)d_in[0];
  const float* w    = (const float*)d_in[1];
  const float* bias = (const float*)d_in[2];
  float* out  = (float*)d_out;
  float* part = (float*)d_ws;

  const size_t plane  = (size_t)T_TOK * NE * sizeof(float);        // 4 MB
  const size_t wbytes = (size_t)NE * HID * 2 * sizeof(_Float16);   // 1.44 MB

  int split = (int)((ws_size - wbytes) / plane);
  if (split > 8) split = 8;
  if (split < 1) split = 1;

  _Float16* wc = (_Float16*)((char*)d_ws + (size_t)split * plane);

  convert_w<<<(NE * (HID / 8) + 255) / 256, 256, 0, stream>>>(w, wc);
  logits_mfma<<<(T_TOK / 128) * split, 256, 0, stream>>>(x, wc, part, split);
  topk_kernel<<<T_TOK / 4, 256, 0, stream>>>(part, bias, out, split);
  count_kernel<<<NE, 256, 0, stream>>>(out + (size_t)T_TOK * TOPK,
                                       out + 2 * (size_t)T_TOK * TOPK);
}